// Round 1
// baseline (896.547 us; speedup 1.0000x reference)
//
#include <hip/hip_runtime.h>

typedef __bf16 bf16x4 __attribute__((ext_vector_type(4)));
typedef __bf16 bf16x8 __attribute__((ext_vector_type(8)));
typedef float  f32x4  __attribute__((ext_vector_type(4)));

#define XS 168   // X tile row stride (elems): 336B, 16B-aligned rows, 2-way-max LDS banks
#define HS 136   // H tile row stride (elems): 272B

__device__ inline f32x4 mfma16(bf16x8 a, bf16x8 b, f32x4 c) {
  return __builtin_amdgcn_mfma_f32_16x16x32_bf16(a, b, c, 0, 0, 0);
}

struct bf2 { __bf16 h, l; };
__device__ inline bf2 split(float x) {
  bf2 r;
  r.h = (__bf16)x;
  r.l = (__bf16)(x - (float)r.h);
  return r;
}

// x = [ef(32) | nf[src](64) | nf[tgt](64)]  (160 = 5 k-chunks of 32)
// h = relu(x @ W1^T + b1) : 128      (4 k-chunks of 32 for GEMM2)
// o = h @ W2^T + b2 : 64
__global__ __launch_bounds__(256, 2) void edge_mlp(
    const int* __restrict__ eidx, const float* __restrict__ nf,
    const float* __restrict__ ef, const float* __restrict__ W1,
    const float* __restrict__ b1, const float* __restrict__ W2,
    const float* __restrict__ b2, float* __restrict__ out, int E)
{
  __shared__ __bf16 sXh[64 * XS];
  __shared__ __bf16 sXl[64 * XS];
  __shared__ __bf16 sHh[64 * HS];
  __shared__ __bf16 sHl[64 * HS];

  const int tid  = threadIdx.x;
  const int lane = tid & 63;
  const int wv   = tid >> 6;     // wave 0..3
  const int l16  = lane & 15;
  const int q    = lane >> 4;    // quad 0..3

  // ---- one-time: W1/W2 hi/lo fragments into registers ----
  // GEMM1: wave wv owns hidden cols [32wv, 32wv+32). B-frag: lane holds
  // W1[j = 32wv+16nt+l16][k = 32kc + 8q .. +8] (8 consecutive k -> contiguous).
  bf16x8 w1h[2][5], w1l[2][5];
#pragma unroll
  for (int nt = 0; nt < 2; ++nt) {
    const int j = 32 * wv + 16 * nt + l16;
#pragma unroll
    for (int kc = 0; kc < 5; ++kc) {
      const float* p = W1 + j * 160 + kc * 32 + q * 8;
#pragma unroll
      for (int i = 0; i < 8; ++i) {
        bf2 s = split(p[i]);
        w1h[nt][kc][i] = s.h;
        w1l[nt][kc][i] = s.l;
      }
    }
  }
  // GEMM2: wave wv owns out cols [16wv, 16wv+16).
  bf16x8 w2h[4], w2l[4];
  {
    const int o = 16 * wv + l16;
#pragma unroll
    for (int kc = 0; kc < 4; ++kc) {
      const float* p = W2 + o * 128 + kc * 32 + q * 8;
#pragma unroll
      for (int i = 0; i < 8; ++i) {
        bf2 s = split(p[i]);
        w2h[kc][i] = s.h;
        w2l[kc][i] = s.l;
      }
    }
  }
  const float b1j0 = b1[32 * wv + l16];
  const float b1j1 = b1[32 * wv + 16 + l16];
  const float b2o  = b2[16 * wv + l16];

  const float4* ef4 = (const float4*)ef;
  const float4* nf4 = (const float4*)nf;

  const int eL = tid >> 2;   // 0..63: edge within tile (gather phase)
  const int qq = tid & 3;    // 4 threads/edge, 10 float4 each
  const int ntiles = (E + 63) >> 6;

  for (int tile = blockIdx.x; tile < ntiles; tile += gridDim.x) {
    const int e0 = tile << 6;

    // ---- P0: gather + hi/lo split X tile into LDS ----
    {
      int e = e0 + eL;
      if (e >= E) e = E - 1;  // duplicate work on tail, stores are guarded
      const int s = eidx[e];
      const int t = eidx[E + e];
#pragma unroll
      for (int i = 0; i < 10; ++i) {
        const int fi = qq * 10 + i;
        const float4* p = (fi < 8)  ? (ef4 + e * 8 + fi)
                        : (fi < 24) ? (nf4 + s * 16 + (fi - 8))
                                    : (nf4 + t * 16 + (fi - 24));
        const float4 v = *p;
        bf16x4 hv, lv;
        { bf2 s0 = split(v.x); hv[0] = s0.h; lv[0] = s0.l; }
        { bf2 s1 = split(v.y); hv[1] = s1.h; lv[1] = s1.l; }
        { bf2 s2 = split(v.z); hv[2] = s2.h; lv[2] = s2.l; }
        { bf2 s3 = split(v.w); hv[3] = s3.h; lv[3] = s3.l; }
        *(bf16x4*)&sXh[eL * XS + fi * 4] = hv;
        *(bf16x4*)&sXl[eL * XS + fi * 4] = lv;
      }
    }
    __syncthreads();

    // ---- P1: GEMM1 (bf16x3: hi*hi + hi*lo + lo*hi) ----
    f32x4 acc1[4][2];
#pragma unroll
    for (int mt = 0; mt < 4; ++mt)
#pragma unroll
      for (int nt = 0; nt < 2; ++nt)
        acc1[mt][nt] = (f32x4){0.f, 0.f, 0.f, 0.f};

#pragma unroll
    for (int kc = 0; kc < 5; ++kc) {
#pragma unroll
      for (int mt = 0; mt < 4; ++mt) {
        const bf16x8 ah = *(const bf16x8*)&sXh[(16 * mt + l16) * XS + kc * 32 + q * 8];
        const bf16x8 al = *(const bf16x8*)&sXl[(16 * mt + l16) * XS + kc * 32 + q * 8];
#pragma unroll
        for (int nt = 0; nt < 2; ++nt) {
          acc1[mt][nt] = mfma16(ah, w1h[nt][kc], acc1[mt][nt]);
          acc1[mt][nt] = mfma16(ah, w1l[nt][kc], acc1[mt][nt]);
          acc1[mt][nt] = mfma16(al, w1h[nt][kc], acc1[mt][nt]);
        }
      }
    }

    // ---- P2: bias + relu, hi/lo split, transpose H through LDS ----
    // D layout: row = 4q + r (within 16-tile), col = l16.
#pragma unroll
    for (int mt = 0; mt < 4; ++mt) {
#pragma unroll
      for (int nt = 0; nt < 2; ++nt) {
        const int col = 32 * wv + 16 * nt + l16;
        const float bb = nt ? b1j1 : b1j0;
#pragma unroll
        for (int r = 0; r < 4; ++r) {
          float h = acc1[mt][nt][r] + bb;
          h = fmaxf(h, 0.f);
          bf2 s = split(h);
          const int row = 16 * mt + 4 * q + r;
          sHh[row * HS + col] = s.h;
          sHl[row * HS + col] = s.l;
        }
      }
    }
    __syncthreads();

    // ---- P3: GEMM2 + bias + store ----
    f32x4 acc2[4];
#pragma unroll
    for (int mt = 0; mt < 4; ++mt) acc2[mt] = (f32x4){0.f, 0.f, 0.f, 0.f};
#pragma unroll
    for (int kc = 0; kc < 4; ++kc) {
#pragma unroll
      for (int mt = 0; mt < 4; ++mt) {
        const bf16x8 ah = *(const bf16x8*)&sHh[(16 * mt + l16) * HS + kc * 32 + q * 8];
        const bf16x8 al = *(const bf16x8*)&sHl[(16 * mt + l16) * HS + kc * 32 + q * 8];
        acc2[mt] = mfma16(ah, w2h[kc], acc2[mt]);
        acc2[mt] = mfma16(ah, w2l[kc], acc2[mt]);
        acc2[mt] = mfma16(al, w2h[kc], acc2[mt]);
      }
    }
#pragma unroll
    for (int mt = 0; mt < 4; ++mt) {
#pragma unroll
      for (int r = 0; r < 4; ++r) {
        const int e = e0 + 16 * mt + 4 * q + r;
        if (e < E) out[e * 64 + 16 * wv + l16] = acc2[mt][r] + b2o;
      }
    }
    // next P0 write of sX is safe: P0-end barrier of iter i+1 orders it after
    // every wave's P1 reads (they must pass the P2-end barrier of iter i first)
  }
}

extern "C" void kernel_launch(void* const* d_in, const int* in_sizes, int n_in,
                              void* d_out, int out_size, void* d_ws, size_t ws_size,
                              hipStream_t stream) {
  const int*   eidx = (const int*)d_in[0];
  const float* nf   = (const float*)d_in[1];
  const float* ef   = (const float*)d_in[2];
  const float* W1   = (const float*)d_in[3];
  const float* b1   = (const float*)d_in[4];
  const float* W2   = (const float*)d_in[5];
  const float* b2   = (const float*)d_in[6];
  float* out = (float*)d_out;
  const int E = in_sizes[0] / 2;

  dim3 grid(1024), block(256);
  hipLaunchKernelGGL(edge_mlp, grid, block, 0, stream,
                     eidx, nf, ef, W1, b1, W2, b2, out, E);
}

// Round 3
// 728.110 us; speedup vs baseline: 1.2313x; 1.2313x over previous
//
#include <hip/hip_runtime.h>

typedef __bf16 bf16x4 __attribute__((ext_vector_type(4)));
typedef __bf16 bf16x8 __attribute__((ext_vector_type(8)));
typedef float  f32x4  __attribute__((ext_vector_type(4)));
typedef unsigned int u32x4 __attribute__((ext_vector_type(4)));

#define XS  168  // X tile row stride (bf16 elems): 336 B rows, 16B-aligned for b128 reads
#define HS2 132  // H tile row stride (uint32 elems): 128 cols + 4 pad; 528 B rows, 16B-aligned
                 // (R2 bug: was 68 -> rows overlapped. One uint32 per k-element!)

__device__ inline f32x4 mfma16(bf16x8 a, bf16x8 b, f32x4 c) {
  return __builtin_amdgcn_mfma_f32_16x16x32_bf16(a, b, c, 0, 0, 0);
}

struct bf2 { __bf16 h, l; };
__device__ inline bf2 split(float x) {
  bf2 r;
  r.h = (__bf16)x;
  r.l = (__bf16)(x - (float)r.h);  // exact residual in fp32
  return r;
}
__device__ inline unsigned int bfbits(__bf16 x) {
  return (unsigned int)__builtin_bit_cast(unsigned short, x);
}

// x = [ef(32) | nf[src](64) | nf[tgt](64)]  (160 = 5 k-chunks of 32)
// h = relu(x @ W1^T + b1) : 128      (4 k-chunks of 32 for GEMM2)
// o = h @ W2^T + b2 : 64
__global__ __launch_bounds__(256, 2) void edge_mlp(
    const int* __restrict__ eidx, const float* __restrict__ nf,
    const float* __restrict__ ef, const float* __restrict__ W1,
    const float* __restrict__ b1, const float* __restrict__ W2,
    const float* __restrict__ b2, float* __restrict__ out, int E)
{
  __shared__ __bf16 sXh[64 * XS];
  __shared__ __bf16 sXl[64 * XS];
  __shared__ unsigned int sH2[64 * HS2];  // packed (hi | lo<<16), one u32 per element

  const int tid  = threadIdx.x;
  const int lane = tid & 63;
  const int wv   = tid >> 6;     // wave 0..3
  const int l16  = lane & 15;
  const int q    = lane >> 4;    // quad 0..3

  // ---- one-time: W1/W2 hi/lo fragments into registers ----
  bf16x8 w1h[2][5], w1l[2][5];
#pragma unroll
  for (int nt = 0; nt < 2; ++nt) {
    const int j = 32 * wv + 16 * nt + l16;
#pragma unroll
    for (int kc = 0; kc < 5; ++kc) {
      const float* p = W1 + j * 160 + kc * 32 + q * 8;
#pragma unroll
      for (int i = 0; i < 8; ++i) {
        bf2 s = split(p[i]);
        w1h[nt][kc][i] = s.h;
        w1l[nt][kc][i] = s.l;
      }
    }
  }
  bf16x8 w2h[4], w2l[4];
  {
    const int o = 16 * wv + l16;
#pragma unroll
    for (int kc = 0; kc < 4; ++kc) {
      const float* p = W2 + o * 128 + kc * 32 + q * 8;
#pragma unroll
      for (int i = 0; i < 8; ++i) {
        bf2 s = split(p[i]);
        w2h[kc][i] = s.h;
        w2l[kc][i] = s.l;
      }
    }
  }
  const float b1j0 = b1[32 * wv + l16];
  const float b1j1 = b1[32 * wv + 16 + l16];
  const float b2o  = b2[16 * wv + l16];

  const float4* ef4 = (const float4*)ef;
  const float4* nf4 = (const float4*)nf;

  const int eL = tid >> 2;   // 0..63: edge within tile (gather phase)
  const int qq = tid & 3;    // 4 threads/edge; fi = qq + 4i (source uniform per i)
  const int ntiles = (E + 63) >> 6;

  // ---- prefetch pipeline: gather tile's 10 float4 into g ----
  float4 g[10];
  auto gather = [&](int tile_) {
    int e = tile_ * 64 + eL;
    if (e >= E) e = E - 1;               // tail: duplicate work, stores guarded
    const int s = eidx[e];
    const int t = eidx[E + e];
#pragma unroll
    for (int i = 0; i < 10; ++i) {
      const int fi = qq + 4 * i;         // i<2: ef, i<6: nf[src], else nf[tgt]
      const float4* p = (i < 2) ? (ef4 + e * 8 + fi)
                      : (i < 6) ? (nf4 + s * 16 + (fi - 8))
                                : (nf4 + t * 16 + (fi - 24));
      g[i] = *p;
    }
  };

  int tile = blockIdx.x;
  if (tile < ntiles) gather(tile);

  for (; tile < ntiles; tile += gridDim.x) {
    const int e0 = tile << 6;

    // ---- P0': split prefetched regs into LDS ----
#pragma unroll
    for (int i = 0; i < 10; ++i) {
      const int fi = qq + 4 * i;
      const float4 v = g[i];
      bf16x4 hv, lv;
      { bf2 s0 = split(v.x); hv[0] = s0.h; lv[0] = s0.l; }
      { bf2 s1 = split(v.y); hv[1] = s1.h; lv[1] = s1.l; }
      { bf2 s2 = split(v.z); hv[2] = s2.h; lv[2] = s2.l; }
      { bf2 s3 = split(v.w); hv[3] = s3.h; lv[3] = s3.l; }
      *(bf16x4*)&sXh[eL * XS + fi * 4] = hv;
      *(bf16x4*)&sXl[eL * XS + fi * 4] = lv;
    }
    __syncthreads();

    // ---- issue next tile's gather NOW; overlaps all compute below ----
    {
      const int nxt = tile + gridDim.x;
      if (nxt < ntiles) gather(nxt);
    }

    // ---- P1: GEMM1 (bf16x3: hi*hi + hi*lo + lo*hi), mt-pair staged ----
    f32x4 acc1[4][2];
#pragma unroll
    for (int mt = 0; mt < 4; ++mt)
#pragma unroll
      for (int nt = 0; nt < 2; ++nt)
        acc1[mt][nt] = (f32x4){0.f, 0.f, 0.f, 0.f};

#pragma unroll
    for (int kc = 0; kc < 5; ++kc) {
#pragma unroll
      for (int mp = 0; mp < 4; mp += 2) {
        bf16x8 ah[2], al[2];
#pragma unroll
        for (int m = 0; m < 2; ++m) {
          ah[m] = *(const bf16x8*)&sXh[(16 * (mp + m) + l16) * XS + kc * 32 + q * 8];
          al[m] = *(const bf16x8*)&sXl[(16 * (mp + m) + l16) * XS + kc * 32 + q * 8];
        }
#pragma unroll
        for (int m = 0; m < 2; ++m)
#pragma unroll
          for (int nt = 0; nt < 2; ++nt)
            acc1[mp + m][nt] = mfma16(ah[m], w1h[nt][kc], acc1[mp + m][nt]);
#pragma unroll
        for (int m = 0; m < 2; ++m)
#pragma unroll
          for (int nt = 0; nt < 2; ++nt)
            acc1[mp + m][nt] = mfma16(ah[m], w1l[nt][kc], acc1[mp + m][nt]);
#pragma unroll
        for (int m = 0; m < 2; ++m)
#pragma unroll
          for (int nt = 0; nt < 2; ++nt)
            acc1[mp + m][nt] = mfma16(al[m], w1h[nt][kc], acc1[mp + m][nt]);
      }
    }

    // ---- P2: bias+relu, pack (hi|lo) into one b32 per element ----
    // row = 16mt + 4q + r, col = 32wv + 16nt + l16.
    // bank: 4q*132 mod 32 = 16 -> q-pairs on disjoint halves, 2 lanes/bank (free).
#pragma unroll
    for (int mt = 0; mt < 4; ++mt) {
#pragma unroll
      for (int nt = 0; nt < 2; ++nt) {
        const int col = 32 * wv + 16 * nt + l16;
        const float bb = nt ? b1j1 : b1j0;
#pragma unroll
        for (int r = 0; r < 4; ++r) {
          float h = fmaxf(acc1[mt][nt][r] + bb, 0.f);
          bf2 s = split(h);
          sH2[(16 * mt + 4 * q + r) * HS2 + col] = bfbits(s.h) | (bfbits(s.l) << 16);
        }
      }
    }
    __syncthreads();

    // ---- P3: GEMM2 (unpack via v_perm), term-outer across all 4 mt ----
    f32x4 acc2[4];
#pragma unroll
    for (int mt = 0; mt < 4; ++mt) acc2[mt] = (f32x4){0.f, 0.f, 0.f, 0.f};

#pragma unroll
    for (int kc = 0; kc < 4; ++kc) {
      bf16x8 ah[4], al[4];
#pragma unroll
      for (int mt = 0; mt < 4; ++mt) {
        const unsigned int* base = &sH2[(16 * mt + l16) * HS2 + kc * 32 + q * 8];
        const u32x4 u0 = *(const u32x4*)base;
        const u32x4 u1 = *(const u32x4*)(base + 4);
        u32x4 hh, ll;
        hh.x = __builtin_amdgcn_perm(u0.y, u0.x, 0x05040100u);
        hh.y = __builtin_amdgcn_perm(u0.w, u0.z, 0x05040100u);
        hh.z = __builtin_amdgcn_perm(u1.y, u1.x, 0x05040100u);
        hh.w = __builtin_amdgcn_perm(u1.w, u1.z, 0x05040100u);
        ll.x = __builtin_amdgcn_perm(u0.y, u0.x, 0x07060302u);
        ll.y = __builtin_amdgcn_perm(u0.w, u0.z, 0x07060302u);
        ll.z = __builtin_amdgcn_perm(u1.y, u1.x, 0x07060302u);
        ll.w = __builtin_amdgcn_perm(u1.w, u1.z, 0x07060302u);
        ah[mt] = __builtin_bit_cast(bf16x8, hh);
        al[mt] = __builtin_bit_cast(bf16x8, ll);
      }
#pragma unroll
      for (int mt = 0; mt < 4; ++mt) acc2[mt] = mfma16(ah[mt], w2h[kc], acc2[mt]);
#pragma unroll
      for (int mt = 0; mt < 4; ++mt) acc2[mt] = mfma16(ah[mt], w2l[kc], acc2[mt]);
#pragma unroll
      for (int mt = 0; mt < 4; ++mt) acc2[mt] = mfma16(al[mt], w2h[kc], acc2[mt]);
    }

#pragma unroll
    for (int mt = 0; mt < 4; ++mt) {
#pragma unroll
      for (int r = 0; r < 4; ++r) {
        const int e = e0 + 16 * mt + 4 * q + r;
        if (e < E) out[e * 64 + 16 * wv + l16] = acc2[mt][r] + b2o;
      }
    }
  }
}

extern "C" void kernel_launch(void* const* d_in, const int* in_sizes, int n_in,
                              void* d_out, int out_size, void* d_ws, size_t ws_size,
                              hipStream_t stream) {
  const int*   eidx = (const int*)d_in[0];
  const float* nf   = (const float*)d_in[1];
  const float* ef   = (const float*)d_in[2];
  const float* W1   = (const float*)d_in[3];
  const float* b1   = (const float*)d_in[4];
  const float* W2   = (const float*)d_in[5];
  const float* b2   = (const float*)d_in[6];
  float* out = (float*)d_out;
  const int E = in_sizes[0] / 2;

  dim3 grid(1024), block(256);
  hipLaunchKernelGGL(edge_mlp, grid, block, 0, stream,
                     eidx, nf, ef, W1, b1, W2, b2, out, E);
}